// Round 8
// baseline (247.456 us; speedup 1.0000x reference)
//
#include <hip/hip_runtime.h>
#include <math.h>

// NoisyTopkRouter: B=4,S=4096,D=2048,E=64,TOP_K=8
// Split-precision bf16 MFMA (Ah*Bh + Ah*Bl + Al*Bh, err ~1e-5).
// W repacked per-K-chunk contiguous (kills the 64-line/instr gather of r7).
// B-frags stream global->reg (L2-resident); only x staged via LDS.
// Near-tie tokens (gap < TAU) re-computed exactly in fp64.

#define KDIM 2048
#define NEXP 64
#define BM 32
#define BK 32
#define NTHREADS 512
#define NCHUNK (KDIM / BK)   // 64
#define LDT 40               // A-tile row: 32 bf16 + pad -> 80B (uniform-8 banks)
#define LDSC 129
#define TAU 1.5e-4f

typedef __attribute__((ext_vector_type(8))) short short8v;
typedef __attribute__((ext_vector_type(4))) float f32x4;

__device__ __forceinline__ void bsplit(float v, ushort& h, ushort& l) {
  unsigned u = __float_as_uint(v);
  unsigned hu = (u + 0x8000u) & 0xFFFF0000u;   // bf16 round
  h = (ushort)(hu >> 16);
  float r = v - __uint_as_float(hu);           // exact residual
  l = (ushort)((__float_as_uint(r) + 0x8000u) >> 16);
}

// W -> Wpk[c][part][row 0..127][k 0..31] bf16, per-chunk 8KB contiguous tiles.
__global__ __launch_bounds__(256)
void convert_w(const float* __restrict__ Wr, const float* __restrict__ Wn,
               ushort* __restrict__ Wpk) {
  const int g = blockIdx.x * 256 + threadIdx.x;    // 65536 threads x 4 elems
  const int row = g >> 9;                          // 0..127
  const int k0  = (g & 511) << 2;                  // 0..2044
  const int c   = k0 >> 5;
  const int kk  = k0 & 31;
  const float* src = (row < NEXP) ? (Wr + (size_t)row * KDIM + k0)
                                  : (Wn + (size_t)(row - NEXP) * KDIM + k0);
  const float4 v = *(const float4*)src;
  ushort4 h, l;
  bsplit(v.x, h.x, l.x); bsplit(v.y, h.y, l.y);
  bsplit(v.z, h.z, l.z); bsplit(v.w, h.w, l.w);
  *(ushort4*)(Wpk + ((size_t)(c * 2 + 0) * 128 + row) * 32 + kk) = h;
  *(ushort4*)(Wpk + ((size_t)(c * 2 + 1) * 128 + row) * 32 + kk) = l;
}

__global__ __launch_bounds__(NTHREADS, 4)
void router_mfma(const float* __restrict__ x,
                 const ushort* __restrict__ Wpk,
                 const float* __restrict__ Wr,  const float* __restrict__ Wn,
                 const float* __restrict__ br,  const float* __restrict__ bn,
                 const float* __restrict__ noise,
                 float* __restrict__ out_w, float* __restrict__ out_i,
                 float* __restrict__ out_s)
{
  union SM {
    struct { ushort Ah[2][BM][LDT], Al[2][BM][LDT]; } g;  // 10.25 KB
    float sc[BM][LDSC];                                    // 16.5 KB
    struct {
      float  xls[KDIM];
      double part[128][2];
      double nv64[NEXP];
      double pe64[NEXP];
    } r;
  };
  __shared__ SM sm;
  __shared__ int flagcnt;
  __shared__ int flaglist[BM];
  __shared__ double m64s;

  const int tid  = threadIdx.x;
  const int row0 = blockIdx.x * BM;
  if (tid == 0) flagcnt = 0;

  // x staging map (threads 0-255): 8 threads/token, float4 each
  const int ar = tid >> 3;
  const int ak = (tid & 7) << 2;
  const float* xA = x + (size_t)(row0 + ar) * KDIM + ak;

  // wave tiles: wave wid -> cols wid*16..wid*16+15, all 32 token rows
  const int wid  = tid >> 6;
  const int lane = tid & 63;
  const int lr   = lane & 15;
  const int lg   = lane >> 4;

  // B-fragment global base: lane reads Wpk[(c*2+p)*128 + col][lg*8..+7]
  const ushort* Wb = Wpk + (size_t)(wid * 16 + lr) * 32 + lg * 8;
#define BFRAG(c, p) (*(const short8v*)(Wb + ((size_t)(c) * 2 + (p)) * 4096))

  f32x4 acc0 = {0.f, 0.f, 0.f, 0.f}, acc1 = {0.f, 0.f, 0.f, 0.f};
  float4 xr = {0.f, 0.f, 0.f, 0.f};
  short8v bhA, blA, bhB, blB;

  // prologue: B chunks 0,1 -> regs; x chunk 0 -> LDS buf0
  bhA = BFRAG(0, 0); blA = BFRAG(0, 1);
  if (tid < 256) {
    xr = *(const float4*)(xA);
    ushort4 h, l;
    bsplit(xr.x, h.x, l.x); bsplit(xr.y, h.y, l.y);
    bsplit(xr.z, h.z, l.z); bsplit(xr.w, h.w, l.w);
    *(ushort4*)&sm.g.Ah[0][ar][ak] = h;
    *(ushort4*)&sm.g.Al[0][ar][ak] = l;
  }
  bhB = BFRAG(1, 0); blB = BFRAG(1, 1);
  __syncthreads();

  for (int c = 0; c < NCHUNK; c += 2) {
    // ---- even: compute chunk c (buf0, bhA); stage c+1 -> buf1; prefetch c+2
    if (tid < 256) xr = *(const float4*)(xA + (c + 1) * BK);
    {
      const short8v ah0 = *(const short8v*)&sm.g.Ah[0][lr][lg * 8];
      const short8v ah1 = *(const short8v*)&sm.g.Ah[0][16 + lr][lg * 8];
      const short8v al0 = *(const short8v*)&sm.g.Al[0][lr][lg * 8];
      const short8v al1 = *(const short8v*)&sm.g.Al[0][16 + lr][lg * 8];
      acc0 = __builtin_amdgcn_mfma_f32_16x16x32_bf16(ah0, bhA, acc0, 0, 0, 0);
      acc1 = __builtin_amdgcn_mfma_f32_16x16x32_bf16(ah1, bhA, acc1, 0, 0, 0);
      acc0 = __builtin_amdgcn_mfma_f32_16x16x32_bf16(ah0, blA, acc0, 0, 0, 0);
      acc1 = __builtin_amdgcn_mfma_f32_16x16x32_bf16(ah1, blA, acc1, 0, 0, 0);
      acc0 = __builtin_amdgcn_mfma_f32_16x16x32_bf16(al0, bhA, acc0, 0, 0, 0);
      acc1 = __builtin_amdgcn_mfma_f32_16x16x32_bf16(al1, bhA, acc1, 0, 0, 0);
    }
    if (c + 2 < NCHUNK) { bhA = BFRAG(c + 2, 0); blA = BFRAG(c + 2, 1); }
    if (tid < 256) {
      ushort4 h, l;
      bsplit(xr.x, h.x, l.x); bsplit(xr.y, h.y, l.y);
      bsplit(xr.z, h.z, l.z); bsplit(xr.w, h.w, l.w);
      *(ushort4*)&sm.g.Ah[1][ar][ak] = h;
      *(ushort4*)&sm.g.Al[1][ar][ak] = l;
    }
    __syncthreads();

    // ---- odd: compute chunk c+1 (buf1, bhB); stage c+2 -> buf0; prefetch c+3
    if (c + 2 < NCHUNK && tid < 256) xr = *(const float4*)(xA + (c + 2) * BK);
    {
      const short8v ah0 = *(const short8v*)&sm.g.Ah[1][lr][lg * 8];
      const short8v ah1 = *(const short8v*)&sm.g.Ah[1][16 + lr][lg * 8];
      const short8v al0 = *(const short8v*)&sm.g.Al[1][lr][lg * 8];
      const short8v al1 = *(const short8v*)&sm.g.Al[1][16 + lr][lg * 8];
      acc0 = __builtin_amdgcn_mfma_f32_16x16x32_bf16(ah0, bhB, acc0, 0, 0, 0);
      acc1 = __builtin_amdgcn_mfma_f32_16x16x32_bf16(ah1, bhB, acc1, 0, 0, 0);
      acc0 = __builtin_amdgcn_mfma_f32_16x16x32_bf16(ah0, blB, acc0, 0, 0, 0);
      acc1 = __builtin_amdgcn_mfma_f32_16x16x32_bf16(ah1, blB, acc1, 0, 0, 0);
      acc0 = __builtin_amdgcn_mfma_f32_16x16x32_bf16(al0, bhB, acc0, 0, 0, 0);
      acc1 = __builtin_amdgcn_mfma_f32_16x16x32_bf16(al1, bhB, acc1, 0, 0, 0);
    }
    if (c + 3 < NCHUNK) { bhB = BFRAG(c + 3, 0); blB = BFRAG(c + 3, 1); }
    if (c + 2 < NCHUNK && tid < 256) {
      ushort4 h, l;
      bsplit(xr.x, h.x, l.x); bsplit(xr.y, h.y, l.y);
      bsplit(xr.z, h.z, l.z); bsplit(xr.w, h.w, l.w);
      *(ushort4*)&sm.g.Ah[0][ar][ak] = h;
      *(ushort4*)&sm.g.Al[0][ar][ak] = l;
    }
    __syncthreads();
  }

  // C-write: col = lane&15 (+wave offset), row = lg*4 + reg (+16 per m-frag)
#pragma unroll
  for (int rr = 0; rr < 4; ++rr) {
    sm.sc[lg * 4 + rr][wid * 16 + lr]      = acc0[rr];
    sm.sc[16 + lg * 4 + rr][wid * 16 + lr] = acc1[rr];
  }
  __syncthreads();

  // ---------------- fp32 epilogue + near-tie detection (proven) ----------------
  if (tid < BM) {
    const int t = tid;
    const int token = row0 + t;
    const float* nrow = noise + (size_t)token * NEXP;

    for (int e = 0; e < NEXP; ++e) {
      const float rte = sm.sc[t][e] + br[e];
      const float z   = sm.sc[t][e + NEXP] + bn[e];
      const float sp  = fmaxf(z, 0.f) + log1pf(expf(-fabsf(z)));
      sm.sc[t][e] = rte + nrow[e] * sp;
    }
    unsigned long long taken = 0ull;
    float vals9[9]; int idx9[9];
#pragma unroll
    for (int p = 0; p < 9; ++p) {
      float best = -INFINITY; int bi = 0;
      for (int e = 0; e < NEXP; ++e) {
        const float v = sm.sc[t][e];
        const bool cnd = (v > best) && (((taken >> e) & 1ull) == 0ull);
        best = cnd ? v : best;
        bi   = cnd ? e : bi;
      }
      taken |= (1ull << bi);
      vals9[p] = best; idx9[p] = bi;
    }
    bool flagged = false;
#pragma unroll
    for (int p = 0; p < 8; ++p) flagged |= (vals9[p] - vals9[p + 1] < TAU);

    if (flagged) {
      const int s = atomicAdd(&flagcnt, 1);
      flaglist[s] = t;
    } else {
      const float m = vals9[0];
      float ssum = 0.f;
      for (int e = 0; e < NEXP; ++e) {
        const float p = expf(sm.sc[t][e] - m);
        sm.sc[t][e] = p;
        ssum += p;
      }
      float* srow = out_s + (size_t)token * NEXP;
      for (int e = 0; e < NEXP; ++e) srow[e] = sm.sc[t][e] / ssum;
      float pt[8]; float wsum = 0.f;
#pragma unroll
      for (int p = 0; p < 8; ++p) { pt[p] = expf(vals9[p] - m); wsum += pt[p]; }
#pragma unroll
      for (int p = 0; p < 8; ++p) {
        out_w[(size_t)token * 8 + p] = pt[p] / wsum;
        out_i[(size_t)token * 8 + p] = (float)idx9[p];
      }
    }
  }
  __syncthreads();

  // ---------------- fp64 exact refine for flagged tokens (proven) ----------------
  const int nf = flagcnt;
  for (int i = 0; i < nf; ++i) {
    const int t = flaglist[i];
    const int token = row0 + t;
    __syncthreads();
    for (int k = tid * 8; k < KDIM; k += NTHREADS * 8) {
      *(float4*)&sm.r.xls[k]     = *(const float4*)&x[(size_t)token * KDIM + k];
      *(float4*)&sm.r.xls[k + 4] = *(const float4*)&x[(size_t)token * KDIM + k + 4];
    }
    __syncthreads();
    if (tid < 256) {
      const int e = tid & 127, h2 = tid >> 7;
      const float* Wrow = ((e < NEXP) ? (Wr + (size_t)e * KDIM)
                                      : (Wn + (size_t)(e - NEXP) * KDIM)) + h2 * 1024;
      const float* xh = sm.r.xls + h2 * 1024;
      double a0 = 0, a1 = 0, a2 = 0, a3 = 0;
      for (int k = 0; k < 1024; k += 4) {
        const float4 w4 = *(const float4*)&Wrow[k];
        const float4 x4 = *(const float4*)&xh[k];
        a0 = fma((double)x4.x, (double)w4.x, a0);
        a1 = fma((double)x4.y, (double)w4.y, a1);
        a2 = fma((double)x4.z, (double)w4.z, a2);
        a3 = fma((double)x4.w, (double)w4.w, a3);
      }
      sm.r.part[e][h2] = (a0 + a1) + (a2 + a3);
    }
    __syncthreads();
    if (tid < NEXP) {
      const double rte = sm.r.part[tid][0] + sm.r.part[tid][1] + (double)br[tid];
      const double z   = sm.r.part[tid + NEXP][0] + sm.r.part[tid + NEXP][1] + (double)bn[tid];
      const double sp  = fmax(z, 0.0) + log1p(exp(-fabs(z)));
      sm.r.nv64[tid] = rte + (double)noise[(size_t)token * NEXP + tid] * sp;
    }
    __syncthreads();
    if (tid == 0) {
      double m = -1e300;
      for (int e = 0; e < NEXP; ++e) m = fmax(m, sm.r.nv64[e]);
      m64s = m;
    }
    __syncthreads();
    if (tid < NEXP) sm.r.pe64[tid] = exp(sm.r.nv64[tid] - m64s);
    __syncthreads();
    if (tid == 0) {
      double ssum = 0.0;
      for (int e = 0; e < NEXP; ++e) ssum += sm.r.pe64[e];
      float* srow = out_s + (size_t)token * NEXP;
      for (int e = 0; e < NEXP; ++e) srow[e] = (float)(sm.r.pe64[e] / ssum);
      unsigned long long taken = 0ull;
      double pv[8]; int pi[8]; double wsum = 0.0;
#pragma unroll
      for (int p = 0; p < 8; ++p) {
        double best = -1e300; int bi = 0;
        for (int e = 0; e < NEXP; ++e) {
          const double v = sm.r.nv64[e];
          const bool cnd = (v > best) && (((taken >> e) & 1ull) == 0ull);
          best = cnd ? v : best;
          bi   = cnd ? e : bi;
        }
        taken |= (1ull << bi);
        pv[p] = sm.r.pe64[bi]; pi[p] = bi; wsum += pv[p];
      }
#pragma unroll
      for (int p = 0; p < 8; ++p) {
        out_w[(size_t)token * 8 + p] = (float)(pv[p] / wsum);
        out_i[(size_t)token * 8 + p] = (float)pi[p];
      }
    }
  }
}

extern "C" void kernel_launch(void* const* d_in, const int* in_sizes, int n_in,
                              void* d_out, int out_size, void* d_ws, size_t ws_size,
                              hipStream_t stream) {
  const float* x     = (const float*)d_in[0];
  const float* Wr    = (const float*)d_in[1];
  const float* br    = (const float*)d_in[2];
  const float* Wn    = (const float*)d_in[3];
  const float* bn    = (const float*)d_in[4];
  const float* noise = (const float*)d_in[5];

  const int M = in_sizes[0] / KDIM;             // 16384 tokens
  ushort* Wpk = (ushort*)d_ws;                  // [64][2][128][32] bf16 = 1 MB

  float* out   = (float*)d_out;
  float* out_w = out;                            // [M,8]
  float* out_i = out + (size_t)M * 8;            // [M,8] indices as float values
  float* out_s = out + (size_t)M * 16;           // [M,64]

  convert_w<<<dim3(256), dim3(256), 0, stream>>>(Wr, Wn, Wpk);
  router_mfma<<<dim3(M / BM), dim3(NTHREADS), 0, stream>>>(
      x, Wpk, Wr, Wn, br, bn, noise, out_w, out_i, out_s);
}

// Round 9
// 189.706 us; speedup vs baseline: 1.3044x; 1.3044x over previous
//
#include <hip/hip_runtime.h>
#include <math.h>

// NoisyTopkRouter: B=4,S=4096,D=2048,E=64,TOP_K=8
// Split into 3 dispatches for per-phase rocprof attribution:
//   convert_w : W -> per-chunk-packed bf16 hi/lo (Wpk, proven r7/r8)
//   gemm_k1   : split-bf16 MFMA GEMM -> raw scores [M][128] f32 in d_ws
//   epi_k2    : one WAVE per token: noisy logits, softmax, ballot top-9,
//               near-tie tokens refined exactly in lane-parallel fp64.

#define KDIM 2048
#define NEXP 64
#define BM 32
#define KB 64                 // K per main-loop block
#define NKB (KDIM / KB)       // 32
#define TAU 1.5e-4f

typedef __attribute__((ext_vector_type(8))) short short8v;
typedef __attribute__((ext_vector_type(4))) float f32x4;

__device__ __forceinline__ void bsplit(float v, ushort& h, ushort& l) {
  unsigned u = __float_as_uint(v);
  unsigned hu = (u + 0x8000u) & 0xFFFF0000u;   // bf16 round
  h = (ushort)(hu >> 16);
  float r = v - __uint_as_float(hu);           // exact residual
  l = (ushort)((__float_as_uint(r) + 0x8000u) >> 16);
}

// W -> Wpk[c 0..63][part hi/lo][row 0..127][k 0..31] bf16 (8KB/chunk tiles)
__global__ __launch_bounds__(256)
void convert_w(const float* __restrict__ Wr, const float* __restrict__ Wn,
               ushort* __restrict__ Wpk) {
  const int g = blockIdx.x * 256 + threadIdx.x;
  const int row = g >> 9;
  const int k0  = (g & 511) << 2;
  const int c   = k0 >> 5;
  const int kk  = k0 & 31;
  const float* src = (row < NEXP) ? (Wr + (size_t)row * KDIM + k0)
                                  : (Wn + (size_t)(row - NEXP) * KDIM + k0);
  const float4 v = *(const float4*)src;
  ushort4 h, l;
  bsplit(v.x, h.x, l.x); bsplit(v.y, h.y, l.y);
  bsplit(v.z, h.z, l.z); bsplit(v.w, h.w, l.w);
  *(ushort4*)(Wpk + ((size_t)(c * 2 + 0) * 128 + row) * 32 + kk) = h;
  *(ushort4*)(Wpk + ((size_t)(c * 2 + 1) * 128 + row) * 32 + kk) = l;
}

struct BSet { short8v h00, h01, l00, l01, h10, h11, l10, l11; };

__device__ __forceinline__ BSet loadB(const ushort* base, int blk) {
  BSet b;
  const ushort* p0 = base + (size_t)blk * 16384;   // 4 chunk-part tiles of 4096
  b.h00 = *(const short8v*)(p0);
  b.h01 = *(const short8v*)(p0 + 512);
  b.l00 = *(const short8v*)(p0 + 4096);
  b.l01 = *(const short8v*)(p0 + 4096 + 512);
  b.h10 = *(const short8v*)(p0 + 8192);
  b.h11 = *(const short8v*)(p0 + 8192 + 512);
  b.l10 = *(const short8v*)(p0 + 12288);
  b.l11 = *(const short8v*)(p0 + 12288 + 512);
  return b;
}

// A-tile LDS: [32 rows][64 bf16] = 4KB per part per buf; 16B-unit XOR swizzle
#define ALD(arr, P, ROW, KH) \
  (*(const short8v*)((const char*)&arr[P][0] + ((ROW) << 7) + (((((KH)*4 + lg)) ^ ((ROW) & 7)) << 4)))

__global__ __launch_bounds__(512, 4)
void gemm_k1(const float* __restrict__ x, const ushort* __restrict__ Wpk,
             float* __restrict__ scores)
{
  __shared__ ushort AhBuf[2][32 * 64];
  __shared__ ushort AlBuf[2][32 * 64];

  const int tid  = threadIdx.x;
  const int row0 = blockIdx.x * BM;

  // staging map: 512 threads cover one 32x64 f32 chunk, one float4 each
  const int srow  = tid >> 4;
  const int sk4   = (tid & 15) << 2;
  const int sunit = sk4 >> 3;
  const int sbyte = (srow << 7) + ((sunit ^ (srow & 7)) << 4) + ((sk4 & 4) << 1);
  const float* xrow = x + (size_t)(row0 + srow) * KDIM + sk4;

  // wave map: mg = row-group (16 rows), cg = col-group (32 cols)
  const int wid  = tid >> 6;
  const int lane = tid & 63;
  const int lr   = lane & 15;
  const int lg   = lane >> 4;
  const int mg   = wid >> 2;
  const int cg   = wid & 3;
  const int arow = mg * 16 + lr;

  const ushort* Wb = Wpk + (size_t)(cg * 32 + lr) * 32 + lg * 8;

  f32x4 acc0 = {0.f, 0.f, 0.f, 0.f}, acc1 = {0.f, 0.f, 0.f, 0.f};

  // prologue: stage block 0 directly; prefetch x blocks 1,2 and B blocks 0,1
  {
    const float4 x0 = *(const float4*)(xrow);
    ushort4 h, l;
    bsplit(x0.x, h.x, l.x); bsplit(x0.y, h.y, l.y);
    bsplit(x0.z, h.z, l.z); bsplit(x0.w, h.w, l.w);
    *(ushort4*)((char*)&AhBuf[0][0] + sbyte) = h;
    *(ushort4*)((char*)&AlBuf[0][0] + sbyte) = l;
  }
  float4 xq1 = *(const float4*)(xrow + 1 * KB);
  float4 xq2 = *(const float4*)(xrow + 2 * KB);
  BSet bE = loadB(Wb, 0);
  BSet bO = loadB(Wb, 1);
  __syncthreads();

  for (int s = 0; s < NKB; s += 2) {
    // ---- even: compute block s (buf0, bE); stage s+1 -> buf1
    {
      ushort4 h, l;
      bsplit(xq1.x, h.x, l.x); bsplit(xq1.y, h.y, l.y);
      bsplit(xq1.z, h.z, l.z); bsplit(xq1.w, h.w, l.w);
      *(ushort4*)((char*)&AhBuf[1][0] + sbyte) = h;
      *(ushort4*)((char*)&AlBuf[1][0] + sbyte) = l;
    }
    { const int nb = (s + 3 < NKB) ? s + 3 : NKB - 1;
      xq1 = *(const float4*)(xrow + nb * KB); }
    {
      const short8v ah0 = ALD(AhBuf, 0, arow, 0);
      const short8v al0 = ALD(AlBuf, 0, arow, 0);
      acc0 = __builtin_amdgcn_mfma_f32_16x16x32_bf16(ah0, bE.h00, acc0, 0, 0, 0);
      acc1 = __builtin_amdgcn_mfma_f32_16x16x32_bf16(ah0, bE.h01, acc1, 0, 0, 0);
      acc0 = __builtin_amdgcn_mfma_f32_16x16x32_bf16(ah0, bE.l00, acc0, 0, 0, 0);
      acc1 = __builtin_amdgcn_mfma_f32_16x16x32_bf16(ah0, bE.l01, acc1, 0, 0, 0);
      acc0 = __builtin_amdgcn_mfma_f32_16x16x32_bf16(al0, bE.h00, acc0, 0, 0, 0);
      acc1 = __builtin_amdgcn_mfma_f32_16x16x32_bf16(al0, bE.h01, acc1, 0, 0, 0);
      const short8v ah1 = ALD(AhBuf, 0, arow, 1);
      const short8v al1 = ALD(AlBuf, 0, arow, 1);
      acc0 = __builtin_amdgcn_mfma_f32_16x16x32_bf16(ah1, bE.h10, acc0, 0, 0, 0);
      acc1 = __builtin_amdgcn_mfma_f32_16x16x32_bf16(ah1, bE.h11, acc1, 0, 0, 0);
      acc0 = __builtin_amdgcn_mfma_f32_16x16x32_bf16(ah1, bE.l10, acc0, 0, 0, 0);
      acc1 = __builtin_amdgcn_mfma_f32_16x16x32_bf16(ah1, bE.l11, acc1, 0, 0, 0);
      acc0 = __builtin_amdgcn_mfma_f32_16x16x32_bf16(al1, bE.h10, acc0, 0, 0, 0);
      acc1 = __builtin_amdgcn_mfma_f32_16x16x32_bf16(al1, bE.h11, acc1, 0, 0, 0);
    }
    { const int nb = (s + 2 < NKB) ? s + 2 : NKB - 1; bE = loadB(Wb, nb); }
    __syncthreads();

    // ---- odd: compute block s+1 (buf1, bO); stage s+2 -> buf0
    {
      ushort4 h, l;
      bsplit(xq2.x, h.x, l.x); bsplit(xq2.y, h.y, l.y);
      bsplit(xq2.z, h.z, l.z); bsplit(xq2.w, h.w, l.w);
      *(ushort4*)((char*)&AhBuf[0][0] + sbyte) = h;
      *(ushort4*)((char*)&AlBuf[0][0] + sbyte) = l;
    }
    { const int nb = (s + 4 < NKB) ? s + 4 : NKB - 1;
      xq2 = *(const float4*)(xrow + nb * KB); }
    {
      const short8v ah0 = ALD(AhBuf, 1, arow, 0);
      const short8v al0 = ALD(AlBuf, 1, arow, 0);
      acc0 = __builtin_amdgcn_mfma_f32_16x16x32_bf16(ah0, bO.h00, acc0, 0, 0, 0);
      acc1 = __builtin_amdgcn_mfma_f32_16x16x32_bf16(ah0, bO.h01, acc1, 0, 0, 0);
      acc0 = __builtin_amdgcn_mfma_f32_16x16x32_bf16(ah0, bO.l00, acc0, 0, 0, 0);
      acc1 = __builtin_amdgcn_mfma_f32_16x16x32_bf16(ah0, bO.l01, acc1, 0, 0, 0);
      acc0 = __builtin_amdgcn_mfma_f32_16x16x32_bf16(al0, bO.h00, acc0, 0, 0, 0);
      acc1 = __builtin_amdgcn_mfma_f32_16x16x32_bf16(al0, bO.h01, acc1, 0, 0, 0);
      const short8v ah1 = ALD(AhBuf, 1, arow, 1);
      const short8v al1 = ALD(AlBuf, 1, arow, 1);
      acc0 = __builtin_amdgcn_mfma_f32_16x16x32_bf16(ah1, bO.h10, acc0, 0, 0, 0);
      acc1 = __builtin_amdgcn_mfma_f32_16x16x32_bf16(ah1, bO.h11, acc1, 0, 0, 0);
      acc0 = __builtin_amdgcn_mfma_f32_16x16x32_bf16(ah1, bO.l10, acc0, 0, 0, 0);
      acc1 = __builtin_amdgcn_mfma_f32_16x16x32_bf16(ah1, bO.l11, acc1, 0, 0, 0);
      acc0 = __builtin_amdgcn_mfma_f32_16x16x32_bf16(al1, bO.h10, acc0, 0, 0, 0);
      acc1 = __builtin_amdgcn_mfma_f32_16x16x32_bf16(al1, bO.h11, acc1, 0, 0, 0);
    }
    { const int nb = (s + 3 < NKB) ? s + 3 : NKB - 1; bO = loadB(Wb, nb); }
    __syncthreads();
  }

  // C layout: col = lane&15, row = (lane>>4)*4 + reg (verified r7/r8)
#pragma unroll
  for (int rr = 0; rr < 4; ++rr) {
    const int trow = row0 + mg * 16 + lg * 4 + rr;
    scores[(size_t)trow * 128 + cg * 32 + lr]      = acc0[rr];
    scores[(size_t)trow * 128 + cg * 32 + 16 + lr] = acc1[rr];
  }
}

// one wave per token: 8 waves/block, 2048 blocks
__global__ __launch_bounds__(512, 4)
void epi_k2(const float* __restrict__ scores, const float* __restrict__ x,
            const float* __restrict__ Wr, const float* __restrict__ Wn,
            const float* __restrict__ br, const float* __restrict__ bn,
            const float* __restrict__ noise,
            float* __restrict__ out_w, float* __restrict__ out_i,
            float* __restrict__ out_s)
{
  const int wid  = threadIdx.x >> 6;
  const int lane = threadIdx.x & 63;
  const int t    = blockIdx.x * 8 + wid;

  const float sr = scores[(size_t)t * 128 + lane];
  const float sn = scores[(size_t)t * 128 + 64 + lane];
  const float z  = sn + bn[lane];
  const float sp = fmaxf(z, 0.f) + log1pf(expf(-fabsf(z)));
  const float v  = sr + br[lane] + noise[(size_t)t * NEXP + lane] * sp;

  float m = v;
#pragma unroll
  for (int d = 32; d; d >>= 1) m = fmaxf(m, __shfl_xor(m, d));
  const float p = expf(v - m);
  float sum = p;
#pragma unroll
  for (int d = 32; d; d >>= 1) sum += __shfl_xor(sum, d);
  out_s[(size_t)t * NEXP + lane] = p / sum;

  float cur = v;
  float vals9[9]; int idx9[9];
#pragma unroll
  for (int it = 0; it < 9; ++it) {
    float mx = cur;
#pragma unroll
    for (int d = 32; d; d >>= 1) mx = fmaxf(mx, __shfl_xor(mx, d));
    const unsigned long long b = __ballot(cur == mx);
    const int li = __ffsll(b) - 1;                 // ties -> lowest index
    vals9[it] = mx; idx9[it] = li;
    if (lane == li) cur = -INFINITY;
  }
  bool flagged = false;
#pragma unroll
  for (int q = 0; q < 8; ++q) flagged |= (vals9[q] - vals9[q + 1] < TAU);

  if (!flagged) {
    float pt[8]; float ws = 0.f;
#pragma unroll
    for (int q = 0; q < 8; ++q) { pt[q] = expf(vals9[q] - m); ws += pt[q]; }
    if (lane < 8) {
      out_w[(size_t)t * 8 + lane] = pt[lane] / ws;
      out_i[(size_t)t * 8 + lane] = (float)idx9[lane];
    }
    return;
  }

  // ---- rare exact fp64 refine, lane-parallel: lane owns expert row `lane`
  const float* xr  = x + (size_t)t * KDIM;
  const float* wrr = Wr + (size_t)lane * KDIM;
  const float* wnr = Wn + (size_t)lane * KDIM;
  double a0 = 0, a1 = 0, a2 = 0, a3 = 0, c0 = 0, c1 = 0, c2 = 0, c3 = 0;
  for (int k = 0; k < KDIM; k += 4) {
    const float4 xv = *(const float4*)(xr + k);
    const float4 wv = *(const float4*)(wrr + k);
    const float4 nv = *(const float4*)(wnr + k);
    a0 = fma((double)xv.x, (double)wv.x, a0);
    a1 = fma((double)xv.y, (double)wv.y, a1);
    a2 = fma((double)xv.z, (double)wv.z, a2);
    a3 = fma((double)xv.w, (double)wv.w, a3);
    c0 = fma((double)xv.x, (double)nv.x, c0);
    c1 = fma((double)xv.y, (double)nv.y, c1);
    c2 = fma((double)xv.z, (double)nv.z, c2);
    c3 = fma((double)xv.w, (double)nv.w, c3);
  }
  const double rte = ((a0 + a1) + (a2 + a3)) + (double)br[lane];
  const double zz  = ((c0 + c1) + (c2 + c3)) + (double)bn[lane];
  const double spd = fmax(zz, 0.0) + log1p(exp(-fabs(zz)));
  const double nv64 = rte + (double)noise[(size_t)t * NEXP + lane] * spd;

  double md = nv64;
#pragma unroll
  for (int d = 32; d; d >>= 1) md = fmax(md, __shfl_xor(md, d));
  const double pe = exp(nv64 - md);
  double sd = pe;
#pragma unroll
  for (int d = 32; d; d >>= 1) sd += __shfl_xor(sd, d);
  out_s[(size_t)t * NEXP + lane] = (float)(pe / sd);

  double curd = nv64;
  double pv8[8]; int pi8[8]; double wsd = 0.0;
#pragma unroll
  for (int it = 0; it < 8; ++it) {
    double mx = curd;
#pragma unroll
    for (int d = 32; d; d >>= 1) mx = fmax(mx, __shfl_xor(mx, d));
    const unsigned long long b = __ballot(curd == mx);
    const int li = __ffsll(b) - 1;
    pv8[it] = __shfl(pe, li); pi8[it] = li; wsd += pv8[it];
    if (lane == li) curd = -1e300;
  }
  if (lane < 8) {
    out_w[(size_t)t * 8 + lane] = (float)(pv8[lane] / wsd);
    out_i[(size_t)t * 8 + lane] = (float)pi8[lane];
  }
}

extern "C" void kernel_launch(void* const* d_in, const int* in_sizes, int n_in,
                              void* d_out, int out_size, void* d_ws, size_t ws_size,
                              hipStream_t stream) {
  const float* x     = (const float*)d_in[0];
  const float* Wr    = (const float*)d_in[1];
  const float* br    = (const float*)d_in[2];
  const float* Wn    = (const float*)d_in[3];
  const float* bn    = (const float*)d_in[4];
  const float* noise = (const float*)d_in[5];

  const int M = in_sizes[0] / KDIM;                  // 16384 tokens
  float*  scores = (float*)d_ws;                     // [M][128] f32 = 8 MB
  ushort* Wpk    = (ushort*)(scores + (size_t)M * 128);  // 1 MB packed W

  float* out   = (float*)d_out;
  float* out_w = out;                                // [M,8]
  float* out_i = out + (size_t)M * 8;                // [M,8] indices as floats
  float* out_s = out + (size_t)M * 16;               // [M,64]

  convert_w<<<dim3(256), dim3(256), 0, stream>>>(Wr, Wn, Wpk);
  gemm_k1<<<dim3(M / BM), dim3(512), 0, stream>>>(x, Wpk, scores);
  epi_k2<<<dim3(M / 8), dim3(512), 0, stream>>>(scores, x, Wr, Wn, br, bn,
                                                noise, out_w, out_i, out_s);
}